// Round 5
// baseline (74.049 us; speedup 1.0000x reference)
//
#include <hip/hip_runtime.h>
#include <math.h>

// WildcatPool2d: x[32,64,64,512] fp32 -> out[32,512] fp32
// out[b,c] = mean(top20 over 4096 spatial) + mean(bottom20 over 4096 spatial)
//
// Round 5: rounds 1-4 all capped at ~3.8 TB/s with 4B/lane scalar strided
// loads. Switch to global_load_lds width=16 (the m193 +67% lever): block =
// 512 threads owns 64 channels x 4096 rows; each wave owns a 512-row slice
// with a wave-private double-buffered 8KB LDS tile (no main-loop barriers,
// counted vmcnt(8) only). Linear gload_lds dest == row-major [32][64] tile;
// ds_read tile[r*64+lane] is 2-way-bank (free). DRAM chunks 128B->256B,
// bytes per vmcnt entry 256B->1KB.

constexpr int CH     = 512;   // channels
constexpr int NR     = 4096;  // H*W
constexpr int K      = 20;
constexpr int CHB    = 64;    // channels per block
constexpr int TROWS  = 32;    // rows per tile
constexpr int NT     = 16;    // tiles per wave (512 rows / 32)
constexpr int TFLOATS = TROWS * CHB;   // 2048 floats = 8 KB

__device__ __forceinline__ void ce_desc(float& a, float& b) {
  float hi = fmaxf(a, b);
  float lo = fminf(a, b);
  a = hi; b = lo;
}
__device__ __forceinline__ void ce_asc(float& a, float& b) {
  float lo = fminf(a, b);
  float hi = fmaxf(a, b);
  a = lo; b = hi;
}

__device__ __forceinline__ void sort32_desc(float* v) {
  #pragma unroll
  for (int k = 2; k <= 32; k <<= 1) {
    #pragma unroll
    for (int j = k >> 1; j > 0; j >>= 1) {
      #pragma unroll
      for (int i = 0; i < 32; ++i) {
        int l = i ^ j;
        if (l > i) {
          if ((i & k) == 0) ce_desc(v[i], v[l]);
          else              ce_asc(v[i], v[l]);
        }
      }
    }
  }
}
__device__ __forceinline__ void clean32_desc(float* v) {
  #pragma unroll
  for (int j = 16; j > 0; j >>= 1) {
    #pragma unroll
    for (int i = 0; i < 32; ++i) {
      int l = i ^ j;
      if (l > i) ce_desc(v[i], v[l]);
    }
  }
}
__device__ __forceinline__ void clean32_asc(float* v) {
  #pragma unroll
  for (int j = 16; j > 0; j >>= 1) {
    #pragma unroll
    for (int i = 0; i < 32; ++i) {
      int l = i ^ j;
      if (l > i) ce_asc(v[i], v[l]);
    }
  }
}
__device__ __forceinline__ void merge_top(float* top, const float* d) {
  #pragma unroll
  for (int i = 0; i < 32; ++i) top[i] = fmaxf(top[i], d[31 - i]);
  clean32_desc(top);
}
__device__ __forceinline__ void merge_bot(float* bot, const float* d) {
  #pragma unroll
  for (int i = 0; i < 32; ++i) bot[i] = fminf(bot[i], d[i]);
  clean32_asc(bot);
}

__device__ __forceinline__ void gload16(const float* g, float* l) {
  __builtin_amdgcn_global_load_lds(
      (const __attribute__((address_space(1))) void*)g,
      (__attribute__((address_space(3))) void*)l,
      16, 0, 0);
}

__global__ __launch_bounds__(512, 2)
void wildcat_topk_kernel(const float* __restrict__ x, float* __restrict__ out) {
  __shared__ float smem[2 * 8 * TFLOATS];   // 128 KB: 8 waves x 2 bufs x 8 KB

  // XCD-chunked swizzle: XCD i (hw round-robin %8) gets logical blocks
  // [i*32, i*32+32) = 4 whole b's, all 8 channel slices -> dense streams.
  const int lb    = (blockIdx.x & 7) * 32 + (blockIdx.x >> 3);  // bijective, 256=8*32
  const int b     = lb >> 3;
  const int cbase = (lb & 7) * CHB;
  const int w     = threadIdx.x >> 6;    // wave 0..7 = row-slice
  const int lane  = threadIdx.x & 63;    // lane = channel within slice

  const float* xb = x + (size_t)b * NR * CH + cbase;
  const int row0  = w * 512;
  float* wbuf = &smem[w * 2 * TFLOATS];

  // issue tile t (rows row0 + t*32 .. +32) into wave-private buf (t&1).
  // per instr i: 4 rows x 64 ch = 1 KB. lane -> row 4i+(lane>>4), ch 4*(lane&15).
  // linear LDS dest lands float (r,c) at tile[r*64+c] (row-major [32][64]).
  auto issue = [&](int t) {
    float* dst = wbuf + (t & 1) * TFLOATS;
    const float* src = xb + (size_t)(row0 + t * TROWS + (lane >> 4)) * CH
                          + (lane & 15) * 4;
    #pragma unroll
    for (int i = 0; i < 8; ++i)
      gload16(src + (size_t)i * 4 * CH, dst + i * 256);
  };

  float top[32], bot[32];

  issue(0);
  issue(1);

  #pragma unroll 1
  for (int t = 0; t < NT; ++t) {
    // wait for tile t (oldest 8 entries); tile t+1's 8 stay in flight
    if (t < NT - 1) asm volatile("s_waitcnt vmcnt(8)" ::: "memory");
    else            asm volatile("s_waitcnt vmcnt(0)" ::: "memory");

    const float* tb = wbuf + (t & 1) * TFLOATS;
    float v[32];
    #pragma unroll
    for (int r = 0; r < 32; ++r) v[r] = tb[r * 64 + lane];   // 2-way bank: free

    // ds_reads must land in VGPRs before buf (t&1) is overwritten by t+2
    asm volatile("s_waitcnt lgkmcnt(0)" ::: "memory");
    if (t + 2 < NT) issue(t + 2);
    __builtin_amdgcn_sched_barrier(0);   // pin issue before the sort

    sort32_desc(v);
    if (t == 0) {
      #pragma unroll
      for (int i = 0; i < 32; ++i) { top[i] = v[i]; bot[i] = v[31 - i]; }
    } else {
      merge_top(top, v);
      merge_bot(bot, v);
    }
  }

  // --- cross-wave tree merge via LDS: 8 -> 4 -> 2 -> 1 (pad 65 = no conflicts)
  __syncthreads();
  #pragma unroll
  for (int half = 4; half >= 1; half >>= 1) {
    if (w >= half && w < 2 * half) {
      float* dst = &smem[((w - half) * 64 + lane) * 65];
      #pragma unroll
      for (int i = 0; i < 32; ++i) { dst[i] = top[i]; dst[32 + i] = bot[i]; }
    }
    __syncthreads();
    if (w < half) {
      const float* src = &smem[(w * 64 + lane) * 65];
      float pt[32], pb[32];
      #pragma unroll
      for (int i = 0; i < 32; ++i) { pt[i] = src[i]; pb[i] = src[32 + i]; }
      #pragma unroll
      for (int i = 0; i < 32; ++i) top[i] = fmaxf(top[i], pt[31 - i]);
      clean32_desc(top);
      #pragma unroll
      for (int i = 0; i < 32; ++i) bot[i] = fminf(bot[i], pb[31 - i]);
      clean32_asc(bot);
    }
    __syncthreads();
  }

  if (w == 0) {
    float s = 0.f;
    #pragma unroll
    for (int i = 0; i < K; ++i) s += top[i] + bot[i];
    out[(size_t)b * CH + cbase + lane] = s * (1.0f / K);
  }
}

extern "C" void kernel_launch(void* const* d_in, const int* in_sizes, int n_in,
                              void* d_out, int out_size, void* d_ws, size_t ws_size,
                              hipStream_t stream) {
  const float* x = (const float*)d_in[0];
  float* out = (float*)d_out;
  // grid: 32 (B) * 8 channel-slices = 256 blocks = 1 block/CU, all co-resident
  hipLaunchKernelGGL(wildcat_topk_kernel, dim3(256), dim3(512), 0, stream, x, out);
}